// Round 1
// baseline (4669.467 us; speedup 1.0000x reference)
//
#include <hip/hip_runtime.h>
#include <math.h>

// B=512, N=128, E=256, H=8, D=32. All fp32 (argmax fidelity requires it).
//
// Decomposition:
//  qkv GEMM folded:  k = emb@W1+b1, v = emb@W2+b2
//  lk2 = emb@Wc + bc  where Wc = W3·Wmlp^T  (folds x=ctx@Wmlp into logits)
//  c[b,n] = emb[b,n]·(W3@bmlp) + b3·bmlp    (bias part of folded logits)
//  stepq = emb@Wstep[E:2E]  ;  qbase = fixed + first@Wstep[0:E] + bstep
//  rollout: 512 persistent blocks (one per batch elem), 127 steps in-kernel.
//
// Workspace layout (floats): k | v | lk2 | qbase | cvec | Wc | bc | wc2 | cconst | stepq
// stepq is optional (fallback recomputes q via GEMV per step) if ws is small.

#define B_ 512
#define N_ 128
#define E_ 256
#define H_ 8
#define D_ 32
#define NEG (-1.0e9f)
#define CLIPV 10.0f
#define SCALE 0.17677669529663688110f  /* 1/sqrt(32), fp32-rounded */

// ---------------------------------------------------------------- K0: weight folds
__global__ void k0_prep(const float* __restrict__ Wqkv, const float* __restrict__ bqkv,
                        const float* __restrict__ Wmlp, const float* __restrict__ bmlp,
                        float* __restrict__ Wc, float* __restrict__ bc,
                        float* __restrict__ wc2, float* __restrict__ cconst) {
  int t = threadIdx.x;
  int blk = blockIdx.x;
  __shared__ float row_s[E_];
  if (blk < E_) {
    // Wc[g][f] = sum_e W3[g][e] * Wmlp[f][e]
    int g = blk;
    row_s[t] = Wqkv[g * 768 + 512 + t];
    __syncthreads();
    int f = t;
    const float4* wm4 = (const float4*)(Wmlp + f * E_);
    const float4* w34 = (const float4*)row_s;
    float acc = 0.f;
#pragma unroll 8
    for (int j = 0; j < E_ / 4; ++j) {
      float4 a = w34[j]; float4 bv = wm4[j];
      acc += a.x * bv.x + a.y * bv.y + a.z * bv.z + a.w * bv.w;
    }
    Wc[g * E_ + f] = acc;
  } else {
    // bc[f] = sum_e b3[e]*Wmlp[f][e];  wc2[g] = sum_e W3[g][e]*bmlp[e]
    int f = t;
    float a1 = 0.f, a2 = 0.f;
    for (int e = 0; e < E_; ++e) {
      a1 += bqkv[512 + e] * Wmlp[f * E_ + e];
      a2 += Wqkv[f * 768 + 512 + e] * bmlp[e];
    }
    bc[f] = a1;
    wc2[f] = a2;
    if (t == 0) {
      float c = 0.f;
      for (int e = 0; e < E_; ++e) c += bqkv[512 + e] * bmlp[e];
      *cconst = c;
    }
  }
}

// ---------------------------------------------------------------- K1: fused precompute GEMM
// out = emb(65536x256) @ {W1,W2,Wc,WstepBot} -> k, v, lk2, stepq. A-tile (64 rows, full K)
// staged k-major in 64KB LDS; B streamed from L2 (all B matrices total ~1MB, L2-hot).
__global__ __launch_bounds__(256, 2)
void k_gemm(const float* __restrict__ emb, const float* __restrict__ Wqkv,
            const float* __restrict__ bqkv, const float* __restrict__ Wstep,
            const float* __restrict__ Wc, const float* __restrict__ bc,
            float* __restrict__ kk_, float* __restrict__ vv_,
            float* __restrict__ lk2, float* __restrict__ sq, int ncc) {
  __shared__ float As[256 * 64];  // [kk][m], exactly 64 KiB
  int t = threadIdx.x;
  int r0 = blockIdx.x * 64;
  {
    int m = t >> 2;           // 0..63
    int c0 = t & 3;
    const float4* e4 = (const float4*)emb;
#pragma unroll
    for (int p = 0; p < 16; ++p) {
      int c4 = c0 + p * 4;    // float4 column 0..63
      float4 a = e4[(size_t)(r0 + m) * 64 + c4];
      As[(c4 * 4 + 0) * 64 + m] = a.x;
      As[(c4 * 4 + 1) * 64 + m] = a.y;
      As[(c4 * 4 + 2) * 64 + m] = a.z;
      As[(c4 * 4 + 3) * 64 + m] = a.w;
    }
  }
  __syncthreads();
  int tx = t & 15, ty = t >> 4;
  const float4* As4 = (const float4*)As;
  for (int cc = 0; cc < ncc; ++cc) {
    const float* Bp; int ldb4; const float* bias; float* outp;
    int colbase = (cc & 1) * 128;
    switch (cc >> 1) {
      case 0:  Bp = Wqkv + colbase;          ldb4 = 192; bias = bqkv + colbase;       outp = kk_; break;
      case 1:  Bp = Wqkv + 256 + colbase;    ldb4 = 192; bias = bqkv + 256 + colbase; outp = vv_; break;
      case 2:  Bp = Wc + colbase;            ldb4 = 64;  bias = bc + colbase;         outp = lk2; break;
      default: Bp = Wstep + 65536 + colbase; ldb4 = 64;  bias = nullptr;              outp = sq;  break;
    }
    const float4* B4 = (const float4*)Bp;
    float acc[4][8];
#pragma unroll
    for (int i = 0; i < 4; ++i)
#pragma unroll
      for (int j = 0; j < 8; ++j) acc[i][j] = 0.f;

#pragma unroll 4
    for (int kk = 0; kk < 256; ++kk) {
      float4 b0 = B4[kk * ldb4 + tx * 2];
      float4 b1 = B4[kk * ldb4 + tx * 2 + 1];
      float4 av = As4[kk * 16 + ty];
      float a_[4] = {av.x, av.y, av.z, av.w};
#pragma unroll
      for (int i = 0; i < 4; ++i) {
        acc[i][0] += a_[i] * b0.x; acc[i][1] += a_[i] * b0.y;
        acc[i][2] += a_[i] * b0.z; acc[i][3] += a_[i] * b0.w;
        acc[i][4] += a_[i] * b1.x; acc[i][5] += a_[i] * b1.y;
        acc[i][6] += a_[i] * b1.z; acc[i][7] += a_[i] * b1.w;
      }
    }
    float bj[8];
#pragma unroll
    for (int j = 0; j < 8; ++j) bj[j] = bias ? bias[tx * 8 + j] : 0.f;
#pragma unroll
    for (int i = 0; i < 4; ++i) {
      int row = r0 + ty * 4 + i;
      float4 o0 = make_float4(acc[i][0] + bj[0], acc[i][1] + bj[1], acc[i][2] + bj[2], acc[i][3] + bj[3]);
      float4 o1 = make_float4(acc[i][4] + bj[4], acc[i][5] + bj[5], acc[i][6] + bj[6], acc[i][7] + bj[7]);
      float4* o4 = (float4*)(outp + (size_t)row * 256 + colbase + tx * 8);
      o4[0] = o0; o4[1] = o1;
    }
  }
}

// ---------------------------------------------------------------- K2: qbase per b
__global__ void k_qbase(const float* __restrict__ emb, const float* __restrict__ Wfix,
                        const float* __restrict__ bfix, const float* __restrict__ Wstep,
                        const float* __restrict__ bstep, float* __restrict__ qbase) {
  int b = blockIdx.x, t = threadIdx.x;
  __shared__ float ge[E_], fi[E_];
  const float* eb = emb + (size_t)b * N_ * E_;
  float s = 0.f;
#pragma unroll 8
  for (int n = 0; n < N_; ++n) s += eb[n * E_ + t];
  ge[t] = s * (1.0f / 128.0f);
  fi[t] = eb[t];
  __syncthreads();
  float acc = bfix[t] + bstep[t];
#pragma unroll 4
  for (int g = 0; g < E_; ++g)
    acc += ge[g] * Wfix[g * E_ + t] + fi[g] * Wstep[g * E_ + t];
  qbase[b * E_ + t] = acc;
}

// ---------------------------------------------------------------- K3: c[b,n]
__global__ void k_c(const float* __restrict__ emb, const float* __restrict__ wc2,
                    const float* __restrict__ cconst, float* __restrict__ cvec) {
  __shared__ float w[E_];
  int t = threadIdx.x;
  w[t] = wc2[t];
  __syncthreads();
  int row = blockIdx.x * 256 + t;
  const float4* e4 = (const float4*)(emb + (size_t)row * E_);
  const float4* w4 = (const float4*)w;
  float acc = 0.f;
#pragma unroll 8
  for (int j = 0; j < E_ / 4; ++j) {
    float4 a = e4[j], bv = w4[j];
    acc += a.x * bv.x + a.y * bv.y + a.z * bv.z + a.w * bv.w;
  }
  cvec[row] = acc + *cconst;
}

// ---------------------------------------------------------------- K4: persistent rollout
// One block per batch element; 127 greedy steps in-kernel. k/v/lk2 streamed from L2/L3.
__global__ __launch_bounds__(256, 2)
void k_loop(const float* __restrict__ emb, const float* __restrict__ Wstep,
            const float* __restrict__ kk_, const float* __restrict__ vv_,
            const float* __restrict__ lk2, const float* __restrict__ sq,
            const float* __restrict__ qbase, const float* __restrict__ cvec,
            float* __restrict__ out, int has_sq) {
  int b = blockIdx.x, t = threadIdx.x;
  __shared__ float q_s[E_];
  __shared__ float attn_s[H_ * N_];
  __shared__ float ctx_s[E_];
  __shared__ float zpart[2 * N_];
  __shared__ float embc[E_];
  __shared__ float redv[2];
  __shared__ int   redi[2];
  __shared__ float reds[4];
  __shared__ int   vis[N_];
  __shared__ int   cur_s;

  if (t < N_) vis[t] = (t == 0) ? 1 : 0;
  if (t == 0) cur_s = 0;
  float lp = 0.f;
  __syncthreads();

  const float* kb = kk_ + (size_t)b * N_ * E_;
  const float* vb = vv_ + (size_t)b * N_ * E_ + t;
  const float* lb = lk2 + (size_t)b * N_ * E_;
  const float* qb = qbase + b * E_;
  const float* cb = cvec + b * N_;
  const float* eb = emb + (size_t)b * N_ * E_;

  int h = t >> 5;           // head for score phase (32 threads per head)
  int n0 = (t & 31) * 4;    // 4 n's per thread

#pragma unroll 1
  for (int it = 0; it < N_ - 1; ++it) {
    int cur = cur_s;
    // --- phase 1: q = qbase + stepq[current]
    if (has_sq) {
      q_s[t] = qb[t] + sq[((size_t)b * N_ + cur) * E_ + t];
    } else {
      embc[t] = eb[cur * E_ + t];
      __syncthreads();
      float a = qb[t];
#pragma unroll 4
      for (int g = 0; g < E_; ++g) a += embc[g] * Wstep[(E_ + g) * E_ + t];
      q_s[t] = a;
    }
    __syncthreads();

    // --- phase 2: scores + masked softmax (per head, 32-lane groups)
    float qv[32];
    {
      const float4* q4 = (const float4*)(q_s + h * 32);
#pragma unroll
      for (int j = 0; j < 8; ++j) {
        float4 x = q4[j];
        qv[j * 4] = x.x; qv[j * 4 + 1] = x.y; qv[j * 4 + 2] = x.z; qv[j * 4 + 3] = x.w;
      }
    }
    float si[4];
#pragma unroll
    for (int i = 0; i < 4; ++i) {
      int n = n0 + i;
      const float4* k4 = (const float4*)(kb + n * E_ + h * 32);
      float acc = 0.f;
#pragma unroll
      for (int j = 0; j < 8; ++j) {
        float4 x = k4[j];
        acc += qv[j * 4] * x.x + qv[j * 4 + 1] * x.y + qv[j * 4 + 2] * x.z + qv[j * 4 + 3] * x.w;
      }
      acc *= SCALE;
      si[i] = vis[n] ? NEG : acc;
    }
    float m = fmaxf(fmaxf(si[0], si[1]), fmaxf(si[2], si[3]));
#pragma unroll
    for (int o = 16; o > 0; o >>= 1) m = fmaxf(m, __shfl_xor(m, o, 32));
    float ei[4]; float ps = 0.f;
#pragma unroll
    for (int i = 0; i < 4; ++i) { ei[i] = expf(si[i] - m); ps += ei[i]; }
#pragma unroll
    for (int o = 16; o > 0; o >>= 1) ps += __shfl_xor(ps, o, 32);
#pragma unroll
    for (int i = 0; i < 4; ++i) attn_s[h * N_ + n0 + i] = ei[i] / ps;
    __syncthreads();

    // --- phase 4: ctx[e] = sum_n attn[h][n] * v[n][e]   (coalesced over e)
    {
      int h2 = t >> 5;
      const float* ar = attn_s + h2 * N_;
      float acc = 0.f;
#pragma unroll 8
      for (int n = 0; n < N_; ++n) acc += ar[n] * vb[n * E_];
      ctx_s[t] = acc;
    }
    __syncthreads();

    // --- phase 5: z[n] = ctx · lk2[n] + c[n]  (two half-dots per n)
    {
      int n = t & 127, half = t >> 7;
      const float4* l4 = (const float4*)(lb + n * E_ + half * 128);
      const float4* c4 = (const float4*)(ctx_s + half * 128);
      float acc = 0.f;
#pragma unroll 4
      for (int j = 0; j < 32; ++j) {
        float4 x = l4[j], y = c4[j];
        acc += x.x * y.x + x.y * y.y + x.z * y.z + x.w * y.w;
      }
      zpart[t] = acc;
    }
    __syncthreads();

    // --- phase 6: argmax (first-index tiebreak), lse, state update
    float zv = 0.f, zmv = -1e30f;
    if (t < N_) {
      zv = zpart[t] + zpart[t + N_] + cb[t];
      zmv = vis[t] ? -1e30f : zv;
    }
    float val = zmv; int idx = t & 127;
#pragma unroll
    for (int o = 32; o > 0; o >>= 1) {
      float ov = __shfl_xor(val, o);
      int oi = __shfl_xor(idx, o);
      if (ov > val || (ov == val && oi < idx)) { val = ov; idx = oi; }
    }
    if (t == 0 || t == 64) { redv[t >> 6] = val; redi[t >> 6] = idx; }
    __syncthreads();
    float v0 = redv[0], v1 = redv[1]; int i0 = redi[0], i1 = redi[1];
    int action; float vmax;
    if (v1 > v0 || (v1 == v0 && i1 < i0)) { action = i1; vmax = v1; }
    else                                  { action = i0; vmax = v0; }
    float lmax = CLIPV * tanhf(vmax * SCALE);
    float term = 0.f;
    if (t < N_ && !vis[t]) {
      float lg = CLIPV * tanhf(zv * SCALE);   // identical expr as lmax -> exact 1.0 at action
      term = expf(lg - lmax);
    }
    float s = term;
#pragma unroll
    for (int o = 32; o > 0; o >>= 1) s += __shfl_xor(s, o);
    __syncthreads();
    if ((t & 63) == 0) reds[t >> 6] = s;
    __syncthreads();
    if (t == 0) {
      float S = reds[0] + reds[1] + reds[2] + reds[3];
      lp -= logf(S);          // chosen = logit_max - lse = -log(S)
      cur_s = action;
      vis[action] = 1;
    }
    __syncthreads();
  }
  if (t == 0) out[b] = lp;
}

// ---------------------------------------------------------------- launch
extern "C" void kernel_launch(void* const* d_in, const int* in_sizes, int n_in,
                              void* d_out, int out_size, void* d_ws, size_t ws_size,
                              hipStream_t stream) {
  (void)in_sizes; (void)n_in; (void)out_size;
  const float* emb   = (const float*)d_in[0];
  const float* Wqkv  = (const float*)d_in[1];
  const float* bqkv  = (const float*)d_in[2];
  const float* Wfix  = (const float*)d_in[3];
  const float* bfix  = (const float*)d_in[4];
  const float* Wstep = (const float*)d_in[5];
  const float* bstep = (const float*)d_in[6];
  const float* Wmlp  = (const float*)d_in[7];
  const float* bmlp  = (const float*)d_in[8];
  float* out = (float*)d_out;
  float* ws = (float*)d_ws;

  const size_t NBE = (size_t)B_ * N_ * E_;  // 16,777,216 floats
  float* kk_    = ws;
  float* vv_    = ws + NBE;
  float* lk2    = ws + 2 * NBE;
  float* qbase  = ws + 3 * NBE;        // 131072
  float* cvec   = qbase + 131072;      // 65536
  float* Wc     = cvec + 65536;        // 65536
  float* bc     = Wc + 65536;          // 256
  float* wc2    = bc + 256;            // 256
  float* cconst = wc2 + 256;           // (64 pad)
  float* sq     = cconst + 64;         // optional, NBE floats
  size_t need_sq = (size_t)((sq - ws) + NBE) * sizeof(float);
  int has_sq = (ws_size >= need_sq) ? 1 : 0;

  hipLaunchKernelGGL(k0_prep, dim3(257), dim3(256), 0, stream,
                     Wqkv, bqkv, Wmlp, bmlp, Wc, bc, wc2, cconst);
  hipLaunchKernelGGL(k_gemm, dim3(1024), dim3(256), 0, stream,
                     emb, Wqkv, bqkv, Wstep, Wc, bc, kk_, vv_, lk2, sq, has_sq ? 8 : 6);
  hipLaunchKernelGGL(k_qbase, dim3(512), dim3(256), 0, stream,
                     emb, Wfix, bfix, Wstep, bstep, qbase);
  hipLaunchKernelGGL(k_c, dim3(256), dim3(256), 0, stream,
                     emb, wc2, cconst, cvec);
  hipLaunchKernelGGL(k_loop, dim3(512), dim3(256), 0, stream,
                     emb, Wstep, kk_, vv_, lk2, sq, qbase, cvec, out, has_sq);
}